// Round 1
// baseline (482.533 us; speedup 1.0000x reference)
//
#include <hip/hip_runtime.h>

#define DN 384
#define DS 512
#define DMSA 64
#define DH 32
#define DP 128

typedef __bf16 bf16x8 __attribute__((ext_vector_type(8)));
typedef float f32x4 __attribute__((ext_vector_type(4)));

// ---------------- ws layout (bytes) ----------------
// at : 0                  .. 12,582,912   (12288 x 512 bf16, row=(n*32+d), k=s contiguous)
// bt : 12,582,912         .. 25,165,824
// wt : 25,165,824         .. 25,427,968   (128 x 1024 bf16, row=p, k=(d*32+e) contiguous)
// inv: 25,427,968 (4B)
// smf: 25,428,224 (512 f32)
// mkf: 25,430,272 (384 f32)
#define OFF_BT  12582912u
#define OFF_WT  25165824u
#define OFF_INV 25427968u
#define OFF_SMF 25428224u
#define OFF_MKF 25430272u

// ---------------------------------------------------------------------------
// prep: mask normalization (robust to int32 vs byte-packed bool), 1/num_msa,
//       and w_out transpose to bf16 [p][k].
// ---------------------------------------------------------------------------
__global__ __launch_bounds__(128) void prep_kernel(const void* __restrict__ mask_raw,
                                                   const void* __restrict__ msa_mask_raw,
                                                   const float* __restrict__ w_out,
                                                   __bf16* __restrict__ wt,
                                                   float* __restrict__ invp,
                                                   float* __restrict__ smf,
                                                   float* __restrict__ mkf) {
  const int blk = blockIdx.x;
  const int tid = threadIdx.x;
  if (blk == 0) {
    // msa_mask: 512 elements
    __shared__ int sh[128];
    const unsigned int* u = (const unsigned int*)msa_mask_raw;
    int bad = (u[tid] > 1u) ? 1 : 0;   // first 128 ints = 512B, safe for either dtype
    sh[tid] = bad;
    __syncthreads();
    for (int off = 64; off > 0; off >>= 1) {
      if (tid < off) sh[tid] |= sh[tid + off];
      __syncthreads();
    }
    const int int_mode = (sh[0] == 0);
    __syncthreads();
    int cnt = 0;
    for (int q = tid; q < DS; q += 128) {
      float v;
      if (int_mode) v = (((const int*)msa_mask_raw)[q] != 0) ? 1.f : 0.f;
      else          v = (((const unsigned char*)msa_mask_raw)[q] != 0) ? 1.f : 0.f;
      smf[q] = v;
      cnt += (v != 0.f) ? 1 : 0;
    }
    sh[tid] = cnt;
    __syncthreads();
    for (int off = 64; off > 0; off >>= 1) {
      if (tid < off) sh[tid] += sh[tid + off];
      __syncthreads();
    }
    if (tid == 0) {
      float num = (float)sh[0];
      if (num < 1e-5f) num = 1e-5f;
      invp[0] = 1.0f / num;
    }
  } else if (blk == 1) {
    // mask: 384 elements
    __shared__ int sh[128];
    const unsigned int* u = (const unsigned int*)mask_raw;
    int bad = 0;
    if (tid < 96) bad = (u[tid] > 1u) ? 1 : 0;  // first 96 ints = 384B, safe
    sh[tid] = bad;
    __syncthreads();
    for (int off = 64; off > 0; off >>= 1) {
      if (tid < off) sh[tid] |= sh[tid + off];
      __syncthreads();
    }
    const int int_mode = (sh[0] == 0);
    __syncthreads();
    for (int q = tid; q < DN; q += 128) {
      float v;
      if (int_mode) v = (((const int*)mask_raw)[q] != 0) ? 1.f : 0.f;
      else          v = (((const unsigned char*)mask_raw)[q] != 0) ? 1.f : 0.f;
      mkf[q] = v;
    }
  } else {
    // transpose w_out [1024][128] f32 -> wt [128][1024] bf16
    const int k = blk - 2;       // 0..1023
    const int p = tid;           // 0..127
    wt[(size_t)p * 1024 + k] = (__bf16)w_out[(size_t)k * DP + p];
  }
}

// ---------------------------------------------------------------------------
// ln_proj: per (s,n): LayerNorm(64) -> x @ w_hidden(64x64) -> mask/scale ->
// write a^T[(n*32+c)][s], b^T[(n*32+c)][s] as bf16 (k-contiguous for GEMM1).
// p = n*512 + s so a wave spans 64 consecutive s -> contiguous 128B stores.
// ---------------------------------------------------------------------------
__global__ __launch_bounds__(256) void ln_proj_kernel(const float* __restrict__ msa,
                                                      const float* __restrict__ gamma,
                                                      const float* __restrict__ beta,
                                                      const float* __restrict__ w_hidden,
                                                      const float* __restrict__ invp,
                                                      const float* __restrict__ smf,
                                                      __bf16* __restrict__ at,
                                                      __bf16* __restrict__ bt) {
  __shared__ float wl[DMSA * 2 * DH];  // 64x64
  __shared__ float gl[DMSA], bl[DMSA];
  const int tid = threadIdx.x;
  for (int q = tid; q < DMSA * 2 * DH; q += 256) wl[q] = w_hidden[q];
  if (tid < DMSA) { gl[tid] = gamma[tid]; bl[tid] = beta[tid]; }
  __syncthreads();

  const int p = blockIdx.x * 256 + tid;
  const int n = p >> 9;       // /512
  const int s = p & 511;

  const float* mp = msa + ((size_t)s * DN + n) * DMSA;
  float x[64];
  float sum = 0.f, sq = 0.f;
#pragma unroll
  for (int q = 0; q < 16; ++q) {
    float4 v = ((const float4*)mp)[q];
    x[4 * q + 0] = v.x; x[4 * q + 1] = v.y; x[4 * q + 2] = v.z; x[4 * q + 3] = v.w;
    sum += v.x + v.y + v.z + v.w;
    sq  += v.x * v.x + v.y * v.y + v.z * v.z + v.w * v.w;
  }
  const float mu = sum * (1.f / 64.f);
  const float var = sq * (1.f / 64.f) - mu * mu;
  const float rstd = rsqrtf(var + 1e-5f);
#pragma unroll
  for (int d = 0; d < 64; ++d) x[d] = (x[d] - mu) * rstd * gl[d] + bl[d];

  const float sm = smf[s];
  const float sa = sm * invp[0];   // fold 1/num_msa into a

  const size_t outbase = ((size_t)n * DH) * DS + s;
  for (int c = 0; c < DH; ++c) {
    float ha = 0.f, hb = 0.f;
#pragma unroll
    for (int d = 0; d < 64; ++d) {
      ha += x[d] * wl[d * 64 + c];
      hb += x[d] * wl[d * 64 + DH + c];
    }
    at[outbase + (size_t)c * DS] = (__bf16)(ha * sa);
    bt[outbase + (size_t)c * DS] = (__bf16)(hb * sm);
  }
}

// ---------------------------------------------------------------------------
// fused: GEMM1 (128x128xK512 op-tile, 4 waves, 4x4 16x16x32 frags each) then
// GEMM2 (16 pairs x 128, K=1024 vs w_out^T) with pair_mask + b_out epilogue.
// LDS XOR-swizzled to kill the 128B-row bank-conflict trap (guide G4).
// ---------------------------------------------------------------------------
__global__ __launch_bounds__(256) void fused_kernel(const __bf16* __restrict__ at,
                                                    const __bf16* __restrict__ bt,
                                                    const __bf16* __restrict__ wt,
                                                    const float* __restrict__ mkf,
                                                    const float* __restrict__ b_out,
                                                    float* __restrict__ out) {
  __shared__ __align__(16) unsigned char smem[32768];
  uint4* ldsA = (uint4*)smem;                 // [128][8] 16B chunks (phase 1)
  uint4* ldsB = (uint4*)(smem + 16384);       // [128][8]
  __bf16* opl = (__bf16*)smem;                // [128][128] (phase 2, aliased)

  const int tid = threadIdx.x;
  const int l = tid & 63;
  const int w = tid >> 6;
  const int lrow = l & 15;
  const int lk = l >> 4;
  const int wrow = (w >> 1) * 64;
  const int wcol = (w & 1) * 64;
  const int bx = blockIdx.x, by = blockIdx.y;
  const int arow0 = bx * 128, brow0 = by * 128;

  const f32x4 zero = {0.f, 0.f, 0.f, 0.f};
  f32x4 acc[4][4];
#pragma unroll
  for (int i = 0; i < 4; ++i)
#pragma unroll
    for (int j = 0; j < 4; ++j) acc[i][j] = zero;

  const int srow = tid >> 3;   // 0..31
  const int sch = tid & 7;     // 16B chunk within 128B row-slab

  for (int kk = 0; kk < DS; kk += 64) {
    __syncthreads();
#pragma unroll
    for (int r = 0; r < 4; ++r) {
      const int row = r * 32 + srow;
      const uint4 va = *(const uint4*)(at + (size_t)(arow0 + row) * DS + kk + sch * 8);
      const uint4 vb = *(const uint4*)(bt + (size_t)(brow0 + row) * DS + kk + sch * 8);
      const int pc = sch ^ (row & 7);
      ldsA[row * 8 + pc] = va;
      ldsB[row * 8 + pc] = vb;
    }
    __syncthreads();
#pragma unroll
    for (int kc = 0; kc < 2; ++kc) {
      bf16x8 af[4], bfr[4];
      const int c = kc * 4 + lk;
#pragma unroll
      for (int f = 0; f < 4; ++f) {
        const int rowA = wrow + f * 16 + lrow;
        af[f] = *(const bf16x8*)&ldsA[rowA * 8 + (c ^ (rowA & 7))];
        const int rowB = wcol + f * 16 + lrow;
        bfr[f] = *(const bf16x8*)&ldsB[rowB * 8 + (c ^ (rowB & 7))];
      }
#pragma unroll
      for (int fi = 0; fi < 4; ++fi)
#pragma unroll
        for (int fj = 0; fj < 4; ++fj)
          acc[fi][fj] = __builtin_amdgcn_mfma_f32_16x16x32_bf16(af[fi], bfr[fj], acc[fi][fj], 0, 0, 0);
    }
  }

  __syncthreads();
  // op tile -> LDS bf16 (swizzled: 16B chunk ^= row&15, row stride 256B)
#pragma unroll
  for (int fi = 0; fi < 4; ++fi)
#pragma unroll
    for (int fj = 0; fj < 4; ++fj)
#pragma unroll
      for (int r = 0; r < 4; ++r) {
        const int row = wrow + fi * 16 + lk * 4 + r;
        const int col = wcol + fj * 16 + lrow;
        const int pcol = (((col >> 3) ^ (row & 15)) << 3) | (col & 7);
        opl[row * 128 + pcol] = (__bf16)acc[fi][fj][r];
      }
  __syncthreads();

  // GEMM2: A2[pair=il*4+jl][k=d*32+e] from opl; B2 = wt[p][k]; 16x128 out tile.
  f32x4 acc2[2];
  acc2[0] = zero; acc2[1] = zero;
  const int il = lrow >> 2, jl = lrow & 3;
  for (int k2 = 0; k2 < 1024; k2 += 32) {
    const int k = k2 + lk * 8;
    const int row = il * 32 + (k >> 5);
    const int col = jl * 32 + (k & 31);
    const int pcol = (((col >> 3) ^ (row & 15)) << 3) | (col & 7);
    const bf16x8 a2 = *(const bf16x8*)&opl[row * 128 + pcol];
#pragma unroll
    for (int nf = 0; nf < 2; ++nf) {
      const int pp = w * 32 + nf * 16 + lrow;
      const bf16x8 b2 = *(const bf16x8*)(wt + (size_t)pp * 1024 + k);
      acc2[nf] = __builtin_amdgcn_mfma_f32_16x16x32_bf16(a2, b2, acc2[nf], 0, 0, 0);
    }
  }

#pragma unroll
  for (int nf = 0; nf < 2; ++nf) {
#pragma unroll
    for (int r = 0; r < 4; ++r) {
      const int pr = lk * 4 + r;                 // C row = pair
      const int i = bx * 4 + (pr >> 2);
      const int j = by * 4 + (pr & 3);
      const float pm = mkf[i] * mkf[j];
      const int pp = w * 32 + nf * 16 + lrow;
      out[((size_t)i * DN + j) * DP + pp] = acc2[nf][r] * pm + b_out[pp];
    }
  }
}

extern "C" void kernel_launch(void* const* d_in, const int* in_sizes, int n_in,
                              void* d_out, int out_size, void* d_ws, size_t ws_size,
                              hipStream_t stream) {
  const float* msa      = (const float*)d_in[0];
  const void*  mask     = d_in[1];
  const void*  msa_mask = d_in[2];
  const float* gamma    = (const float*)d_in[3];
  const float* beta     = (const float*)d_in[4];
  const float* w_hidden = (const float*)d_in[5];
  const float* w_out    = (const float*)d_in[6];
  const float* b_out    = (const float*)d_in[7];
  float* out = (float*)d_out;

  char* ws = (char*)d_ws;
  __bf16* at  = (__bf16*)ws;
  __bf16* bt  = (__bf16*)(ws + OFF_BT);
  __bf16* wt  = (__bf16*)(ws + OFF_WT);
  float*  inv = (float*)(ws + OFF_INV);
  float*  smf = (float*)(ws + OFF_SMF);
  float*  mkf = (float*)(ws + OFF_MKF);

  prep_kernel<<<1026, 128, 0, stream>>>(mask, msa_mask, w_out, wt, inv, smf, mkf);
  ln_proj_kernel<<<768, 256, 0, stream>>>(msa, gamma, beta, w_hidden, inv, smf, at, bt);
  fused_kernel<<<dim3(96, 96), 256, 0, stream>>>(at, bt, wt, mkf, b_out, out);
}

// Round 2
// 341.140 us; speedup vs baseline: 1.4145x; 1.4145x over previous
//
#include <hip/hip_runtime.h>

#define DN 384
#define DS 512
#define DMSA 64
#define DH 32
#define DP 128

typedef __bf16 bf16x8 __attribute__((ext_vector_type(8)));
typedef __bf16 bf16x4 __attribute__((ext_vector_type(4)));
typedef float f32x4 __attribute__((ext_vector_type(4)));

// ws layout (bytes)
#define OFF_BT  12582912u
#define OFF_WT  25165824u
#define OFF_INV 25427968u
#define OFF_SMF 25428224u
#define OFF_MKF 25430272u

__device__ __forceinline__ void async16(const void* g, void* l) {
  __builtin_amdgcn_global_load_lds((const __attribute__((address_space(1))) unsigned*)g,
                                   (__attribute__((address_space(3))) unsigned*)l, 16, 0, 0);
}

// ---------------------------------------------------------------------------
// prep: mask normalization, 1/num_msa, w_out transpose to bf16 [p][k'=e*32+d].
// ---------------------------------------------------------------------------
__global__ __launch_bounds__(128) void prep_kernel(const void* __restrict__ mask_raw,
                                                   const void* __restrict__ msa_mask_raw,
                                                   const float* __restrict__ w_out,
                                                   __bf16* __restrict__ wt,
                                                   float* __restrict__ invp,
                                                   float* __restrict__ smf,
                                                   float* __restrict__ mkf) {
  const int blk = blockIdx.x;
  const int tid = threadIdx.x;
  if (blk == 0) {
    __shared__ int sh[128];
    const unsigned int* u = (const unsigned int*)msa_mask_raw;
    int bad = (u[tid] > 1u) ? 1 : 0;
    sh[tid] = bad;
    __syncthreads();
    for (int off = 64; off > 0; off >>= 1) {
      if (tid < off) sh[tid] |= sh[tid + off];
      __syncthreads();
    }
    const int int_mode = (sh[0] == 0);
    __syncthreads();
    int cnt = 0;
    for (int q = tid; q < DS; q += 128) {
      float v;
      if (int_mode) v = (((const int*)msa_mask_raw)[q] != 0) ? 1.f : 0.f;
      else          v = (((const unsigned char*)msa_mask_raw)[q] != 0) ? 1.f : 0.f;
      smf[q] = v;
      cnt += (v != 0.f) ? 1 : 0;
    }
    sh[tid] = cnt;
    __syncthreads();
    for (int off = 64; off > 0; off >>= 1) {
      if (tid < off) sh[tid] += sh[tid + off];
      __syncthreads();
    }
    if (tid == 0) {
      float num = (float)sh[0];
      if (num < 1e-5f) num = 1e-5f;
      invp[0] = 1.0f / num;
    }
  } else if (blk == 1) {
    __shared__ int sh[128];
    const unsigned int* u = (const unsigned int*)mask_raw;
    int bad = 0;
    if (tid < 96) bad = (u[tid] > 1u) ? 1 : 0;
    sh[tid] = bad;
    __syncthreads();
    for (int off = 64; off > 0; off >>= 1) {
      if (tid < off) sh[tid] |= sh[tid + off];
      __syncthreads();
    }
    const int int_mode = (sh[0] == 0);
    __syncthreads();
    for (int q = tid; q < DN; q += 128) {
      float v;
      if (int_mode) v = (((const int*)mask_raw)[q] != 0) ? 1.f : 0.f;
      else          v = (((const unsigned char*)mask_raw)[q] != 0) ? 1.f : 0.f;
      mkf[q] = v;
    }
  } else {
    const int kw = blk - 2;       // 0..1023 = d*32+e
    const int p = tid;            // 0..127
    wt[(size_t)p * 1024 + ((kw & 31) * 32 + (kw >> 5))] = (__bf16)w_out[(size_t)kw * DP + p];
  }
}

// ---------------------------------------------------------------------------
// ln_proj: LN(64) -> x@w_hidden -> mask/scale -> at/bt [n*32+c][s] bf16.
// ---------------------------------------------------------------------------
__global__ __launch_bounds__(256) void ln_proj_kernel(const float* __restrict__ msa,
                                                      const float* __restrict__ gamma,
                                                      const float* __restrict__ beta,
                                                      const float* __restrict__ w_hidden,
                                                      const float* __restrict__ invp,
                                                      const float* __restrict__ smf,
                                                      __bf16* __restrict__ at,
                                                      __bf16* __restrict__ bt) {
  __shared__ float wl[DMSA * 2 * DH];
  __shared__ float gl[DMSA], bl[DMSA];
  const int tid = threadIdx.x;
  for (int q = tid; q < DMSA * 2 * DH; q += 256) wl[q] = w_hidden[q];
  if (tid < DMSA) { gl[tid] = gamma[tid]; bl[tid] = beta[tid]; }
  __syncthreads();

  const int p = blockIdx.x * 256 + tid;
  const int n = p >> 9;
  const int s = p & 511;

  const float* mp = msa + ((size_t)s * DN + n) * DMSA;
  float x[64];
  float sum = 0.f, sq = 0.f;
#pragma unroll
  for (int q = 0; q < 16; ++q) {
    float4 v = ((const float4*)mp)[q];
    x[4 * q + 0] = v.x; x[4 * q + 1] = v.y; x[4 * q + 2] = v.z; x[4 * q + 3] = v.w;
    sum += v.x + v.y + v.z + v.w;
    sq  += v.x * v.x + v.y * v.y + v.z * v.z + v.w * v.w;
  }
  const float mu = sum * (1.f / 64.f);
  const float var = sq * (1.f / 64.f) - mu * mu;
  const float rstd = rsqrtf(var + 1e-5f);
#pragma unroll
  for (int d = 0; d < 64; ++d) x[d] = (x[d] - mu) * rstd * gl[d] + bl[d];

  const float sm = smf[s];
  const float sa = sm * invp[0];

  const size_t outbase = ((size_t)n * DH) * DS + s;
  for (int c = 0; c < DH; ++c) {
    float ha = 0.f, hb = 0.f;
#pragma unroll
    for (int d = 0; d < 64; ++d) {
      ha += x[d] * wl[d * 64 + c];
      hb += x[d] * wl[d * 64 + DH + c];
    }
    at[outbase + (size_t)c * DS] = (__bf16)(ha * sa);
    bt[outbase + (size_t)c * DS] = (__bf16)(hb * sm);
  }
}

// ---------------------------------------------------------------------------
// fused: GEMM1 256x256xK512 (8 waves, 128x64/wave, gload_lds + swizzle +
// counted-vmcnt dbuf) -> op tile to LDS [64 pairs][1024+pad] bf16 ->
// GEMM2 64x128xK1024 (2Mx2N frags/wave, B=wt from L2) -> mask+bias epilogue.
// ---------------------------------------------------------------------------
__global__ __launch_bounds__(512, 2) void fused_kernel(const __bf16* __restrict__ at,
                                                       const __bf16* __restrict__ bt,
                                                       const __bf16* __restrict__ wt,
                                                       const float* __restrict__ mkf,
                                                       const float* __restrict__ b_out,
                                                       float* __restrict__ out) {
  // staging: 2 bufs x (A 32KB + B 32KB) = 128KB; aliased: opl2 64x2064B = 129KB
  __shared__ __align__(128) char smem[132096];

  const int tid = threadIdx.x;
  const int l = tid & 63, w = tid >> 6;
  const int lr = l & 15, lk = l >> 4;
  const int wr = w >> 2, wc = w & 3;

  // XCD-aware swizzle: 48 supertiles of 8x6 blocks; blocks orig%8 -> same XCD.
  const int orig = blockIdx.x;
  const int xcd = orig & 7, sidx = orig >> 3;          // sidx 0..287
  const int stl = sidx / 48, u = sidx % 48;            // stl 0..5
  const int stg = xcd + stl * 8;                       // 0..47
  const int stx = stg % 6, sty = stg / 6;
  const int bx = stx * 8 + (u & 7);                    // 0..47
  const int by = sty * 6 + (u >> 3);                   // 0..47

  // staging source bases (pre-swizzled per-lane global addresses)
  const int srow = w * 32 + (l >> 3);                  // + q*8
  const int gch = (l & 7) ^ (l >> 3);                  // logical 16B chunk
  const __bf16* gA = at + (size_t)(bx * 256 + srow) * 512 + gch * 8;
  const __bf16* gB = bt + (size_t)(by * 256 + srow) * 512 + gch * 8;

  f32x4 acc[8][4];
#pragma unroll
  for (int i = 0; i < 8; ++i)
#pragma unroll
    for (int j = 0; j < 4; ++j) acc[i][j] = (f32x4){0.f, 0.f, 0.f, 0.f};

  auto STAGE = [&](int t, int b) {
    const int o = t * 64;
    char* ba = smem + b * 65536 + (w * 4) * 1024;
    char* bb = ba + 32768;
    async16(gA + o,             ba);
    async16(gA + o + 8 * 512,   ba + 1024);
    async16(gA + o + 16 * 512,  ba + 2048);
    async16(gA + o + 24 * 512,  ba + 3072);
    async16(gB + o,             bb);
    async16(gB + o + 8 * 512,   bb + 1024);
    async16(gB + o + 16 * 512,  bb + 2048);
    async16(gB + o + 24 * 512,  bb + 3072);
  };

  auto COMPUTE = [&](int b) {
    const char* A = smem + b * 65536;
    const char* B = A + 32768;
#pragma unroll
    for (int kh = 0; kh < 2; ++kh) {
      const int phys = (kh * 4 + lk) ^ (lr & 7);
      bf16x8 af[8], bfr[4];
#pragma unroll
      for (int fi = 0; fi < 8; ++fi)
        af[fi] = *(const bf16x8*)(A + (wr * 128 + fi * 16 + lr) * 128 + phys * 16);
#pragma unroll
      for (int fj = 0; fj < 4; ++fj)
        bfr[fj] = *(const bf16x8*)(B + (wc * 64 + fj * 16 + lr) * 128 + phys * 16);
#pragma unroll
      for (int fi = 0; fi < 8; ++fi)
#pragma unroll
        for (int fj = 0; fj < 4; ++fj)
          acc[fi][fj] = __builtin_amdgcn_mfma_f32_16x16x32_bf16(af[fi], bfr[fj], acc[fi][fj], 0, 0, 0);
    }
  };

  STAGE(0, 0);
  STAGE(1, 1);
#pragma unroll
  for (int t = 0; t < 8; ++t) {
    if (t < 7) asm volatile("s_waitcnt vmcnt(8)" ::: "memory");
    else       asm volatile("s_waitcnt vmcnt(0)" ::: "memory");
    __builtin_amdgcn_s_barrier();
    COMPUTE(t & 1);
    asm volatile("s_waitcnt lgkmcnt(0)" ::: "memory");
    __builtin_amdgcn_s_barrier();
    if (t < 6) STAGE(t + 2, t & 1);
  }

  // ---- op tile -> LDS bf16 as A2[pair=il*8+jl][k'=e*32+d], row pad +16B ----
#pragma unroll
  for (int fi = 0; fi < 8; ++fi) {
    const int i_l = (wr * 128 + fi * 16) >> 5;          // lane-uniform
    const int dbase = (fi & 1) * 16 + lk * 4;
#pragma unroll
    for (int fj = 0; fj < 4; ++fj) {
      const int col = wc * 64 + fj * 16 + lr;
      const int j_l = col >> 5, e = col & 31;
      const int pair = i_l * 8 + j_l;
      bf16x4 pk;
      pk[0] = (__bf16)acc[fi][fj][0];
      pk[1] = (__bf16)acc[fi][fj][1];
      pk[2] = (__bf16)acc[fi][fj][2];
      pk[3] = (__bf16)acc[fi][fj][3];
      *(bf16x4*)(smem + pair * 2064 + (e * 32 + dbase) * 2) = pk;
    }
  }
  asm volatile("s_waitcnt lgkmcnt(0)" ::: "memory");
  __builtin_amdgcn_s_barrier();

  // ---- GEMM2: C[64 pairs][128 p], K=1024; wave = 2 Mfrags x 2 Nfrags ----
  const int mg = w & 1, ng = w >> 1;                    // ng 0..3
  f32x4 acc2[2][2];
#pragma unroll
  for (int a = 0; a < 2; ++a)
#pragma unroll
    for (int b = 0; b < 2; ++b) acc2[a][b] = (f32x4){0.f, 0.f, 0.f, 0.f};

  for (int kk = 0; kk < 32; ++kk) {
    const int k = kk * 32 + lk * 8;
    bf16x8 a2[2], b2[2];
#pragma unroll
    for (int mf = 0; mf < 2; ++mf) {
      const int pair = mg * 32 + mf * 16 + lr;
      a2[mf] = *(const bf16x8*)(smem + pair * 2064 + k * 2);
    }
#pragma unroll
    for (int nf = 0; nf < 2; ++nf) {
      const int p = ng * 32 + nf * 16 + lr;
      b2[nf] = *(const bf16x8*)(wt + (size_t)p * 1024 + k);
    }
#pragma unroll
    for (int mf = 0; mf < 2; ++mf)
#pragma unroll
      for (int nf = 0; nf < 2; ++nf)
        acc2[mf][nf] = __builtin_amdgcn_mfma_f32_16x16x32_bf16(a2[mf], b2[nf], acc2[mf][nf], 0, 0, 0);
  }

#pragma unroll
  for (int mf = 0; mf < 2; ++mf)
#pragma unroll
    for (int r = 0; r < 4; ++r) {
      const int pair = mg * 32 + mf * 16 + lk * 4 + r;
      const int i = bx * 8 + (pair >> 3);
      const int j = by * 8 + (pair & 7);
      const float pm = mkf[i] * mkf[j];
#pragma unroll
      for (int nf = 0; nf < 2; ++nf) {
        const int p = ng * 32 + nf * 16 + lr;
        out[((size_t)i * DN + j) * DP + p] = acc2[mf][nf][r] * pm + b_out[p];
      }
    }
}

extern "C" void kernel_launch(void* const* d_in, const int* in_sizes, int n_in,
                              void* d_out, int out_size, void* d_ws, size_t ws_size,
                              hipStream_t stream) {
  const float* msa      = (const float*)d_in[0];
  const void*  mask     = d_in[1];
  const void*  msa_mask = d_in[2];
  const float* gamma    = (const float*)d_in[3];
  const float* beta     = (const float*)d_in[4];
  const float* w_hidden = (const float*)d_in[5];
  const float* w_out    = (const float*)d_in[6];
  const float* b_out    = (const float*)d_in[7];
  float* out = (float*)d_out;

  char* ws = (char*)d_ws;
  __bf16* at  = (__bf16*)ws;
  __bf16* bt  = (__bf16*)(ws + OFF_BT);
  __bf16* wt  = (__bf16*)(ws + OFF_WT);
  float*  inv = (float*)(ws + OFF_INV);
  float*  smf = (float*)(ws + OFF_SMF);
  float*  mkf = (float*)(ws + OFF_MKF);

  prep_kernel<<<1026, 128, 0, stream>>>(mask, msa_mask, w_out, wt, inv, smf, mkf);
  ln_proj_kernel<<<768, 256, 0, stream>>>(msa, gamma, beta, w_hidden, inv, smf, at, bt);
  fused_kernel<<<2304, 512, 0, stream>>>(at, bt, wt, mkf, b_out, out);
}

// Round 3
// 332.844 us; speedup vs baseline: 1.4497x; 1.0249x over previous
//
#include <hip/hip_runtime.h>

#define DN 384
#define DS 512
#define DMSA 64
#define DH 32
#define DP 128

typedef __bf16 bf16x8 __attribute__((ext_vector_type(8)));
typedef __bf16 bf16x4 __attribute__((ext_vector_type(4)));
typedef float f32x4 __attribute__((ext_vector_type(4)));

// ws layout (bytes)
#define OFF_BT  12582912u
#define OFF_WT  25165824u
#define OFF_INV 25427968u
#define OFF_SMF 25428224u
#define OFF_MKF 25430272u

__device__ __forceinline__ void async16(const void* g, void* l) {
  __builtin_amdgcn_global_load_lds((const __attribute__((address_space(1))) unsigned*)g,
                                   (__attribute__((address_space(3))) unsigned*)l, 16, 0, 0);
}

// ---------------------------------------------------------------------------
// prep: mask normalization, 1/num_msa, w_out transpose to bf16 [p][k'=e*32+d].
// ---------------------------------------------------------------------------
__global__ __launch_bounds__(128) void prep_kernel(const void* __restrict__ mask_raw,
                                                   const void* __restrict__ msa_mask_raw,
                                                   const float* __restrict__ w_out,
                                                   __bf16* __restrict__ wt,
                                                   float* __restrict__ invp,
                                                   float* __restrict__ smf,
                                                   float* __restrict__ mkf) {
  const int blk = blockIdx.x;
  const int tid = threadIdx.x;
  if (blk == 0) {
    __shared__ int sh[128];
    const unsigned int* u = (const unsigned int*)msa_mask_raw;
    int bad = (u[tid] > 1u) ? 1 : 0;
    sh[tid] = bad;
    __syncthreads();
    for (int off = 64; off > 0; off >>= 1) {
      if (tid < off) sh[tid] |= sh[tid + off];
      __syncthreads();
    }
    const int int_mode = (sh[0] == 0);
    __syncthreads();
    int cnt = 0;
    for (int q = tid; q < DS; q += 128) {
      float v;
      if (int_mode) v = (((const int*)msa_mask_raw)[q] != 0) ? 1.f : 0.f;
      else          v = (((const unsigned char*)msa_mask_raw)[q] != 0) ? 1.f : 0.f;
      smf[q] = v;
      cnt += (v != 0.f) ? 1 : 0;
    }
    sh[tid] = cnt;
    __syncthreads();
    for (int off = 64; off > 0; off >>= 1) {
      if (tid < off) sh[tid] += sh[tid + off];
      __syncthreads();
    }
    if (tid == 0) {
      float num = (float)sh[0];
      if (num < 1e-5f) num = 1e-5f;
      invp[0] = 1.0f / num;
    }
  } else if (blk == 1) {
    __shared__ int sh[128];
    const unsigned int* u = (const unsigned int*)mask_raw;
    int bad = 0;
    if (tid < 96) bad = (u[tid] > 1u) ? 1 : 0;
    sh[tid] = bad;
    __syncthreads();
    for (int off = 64; off > 0; off >>= 1) {
      if (tid < off) sh[tid] |= sh[tid + off];
      __syncthreads();
    }
    const int int_mode = (sh[0] == 0);
    __syncthreads();
    for (int q = tid; q < DN; q += 128) {
      float v;
      if (int_mode) v = (((const int*)mask_raw)[q] != 0) ? 1.f : 0.f;
      else          v = (((const unsigned char*)mask_raw)[q] != 0) ? 1.f : 0.f;
      mkf[q] = v;
    }
  } else {
    const int kw = blk - 2;       // 0..1023 = d*32+e
    const int p = tid;            // 0..127
    wt[(size_t)p * 1024 + ((kw & 31) * 32 + (kw >> 5))] = (__bf16)w_out[(size_t)kw * DP + p];
  }
}

// ---------------------------------------------------------------------------
// ln_proj: LN(64) -> x@w_hidden -> mask/scale -> at/bt [n*32+c][s] bf16.
// ---------------------------------------------------------------------------
__global__ __launch_bounds__(256) void ln_proj_kernel(const float* __restrict__ msa,
                                                      const float* __restrict__ gamma,
                                                      const float* __restrict__ beta,
                                                      const float* __restrict__ w_hidden,
                                                      const float* __restrict__ invp,
                                                      const float* __restrict__ smf,
                                                      __bf16* __restrict__ at,
                                                      __bf16* __restrict__ bt) {
  __shared__ float wl[DMSA * 2 * DH];
  __shared__ float gl[DMSA], bl[DMSA];
  const int tid = threadIdx.x;
  for (int q = tid; q < DMSA * 2 * DH; q += 256) wl[q] = w_hidden[q];
  if (tid < DMSA) { gl[tid] = gamma[tid]; bl[tid] = beta[tid]; }
  __syncthreads();

  const int p = blockIdx.x * 256 + tid;
  const int n = p >> 9;
  const int s = p & 511;

  const float* mp = msa + ((size_t)s * DN + n) * DMSA;
  float x[64];
  float sum = 0.f, sq = 0.f;
#pragma unroll
  for (int q = 0; q < 16; ++q) {
    float4 v = ((const float4*)mp)[q];
    x[4 * q + 0] = v.x; x[4 * q + 1] = v.y; x[4 * q + 2] = v.z; x[4 * q + 3] = v.w;
    sum += v.x + v.y + v.z + v.w;
    sq  += v.x * v.x + v.y * v.y + v.z * v.z + v.w * v.w;
  }
  const float mu = sum * (1.f / 64.f);
  const float var = sq * (1.f / 64.f) - mu * mu;
  const float rstd = rsqrtf(var + 1e-5f);
#pragma unroll
  for (int d = 0; d < 64; ++d) x[d] = (x[d] - mu) * rstd * gl[d] + bl[d];

  const float sm = smf[s];
  const float sa = sm * invp[0];

  const size_t outbase = ((size_t)n * DH) * DS + s;
  for (int c = 0; c < DH; ++c) {
    float ha = 0.f, hb = 0.f;
#pragma unroll
    for (int d = 0; d < 64; ++d) {
      ha += x[d] * wl[d * 64 + c];
      hb += x[d] * wl[d * 64 + DH + c];
    }
    at[outbase + (size_t)c * DS] = (__bf16)(ha * sa);
    bt[outbase + (size_t)c * DS] = (__bf16)(hb * sm);
  }
}

// ---------------------------------------------------------------------------
// fused: GEMM1 256x256xK512 as 16 half-tiles (BK=32) on a 4-slot LDS ring,
// 2 phases/half {ds_read, stage-issue, barrier, lgkm, setprio+16 MFMA, barrier},
// counted vmcnt(8) at half boundaries (T3+T4+T5). Then op->LDS (swizzled) ->
// GEMM2 64x128xK1024 -> pair_mask + b_out epilogue.
// ---------------------------------------------------------------------------
__global__ __launch_bounds__(512, 2) void fused_kernel(const __bf16* __restrict__ at,
                                                       const __bf16* __restrict__ bt,
                                                       const __bf16* __restrict__ wt,
                                                       const float* __restrict__ mkf,
                                                       const float* __restrict__ b_out,
                                                       float* __restrict__ out) {
  // ring: 4 slots x (A 16KB + B 16KB) = 128KB; aliased: opl 64x2064B = 129KB
  __shared__ __align__(128) char smem[132096];

  const int tid = threadIdx.x;
  const int l = tid & 63, w = tid >> 6;
  const int lr = l & 15, lk = l >> 4;
  const int wr = w >> 2, wc = w & 3;

  // XCD-aware swizzle: 48 supertiles of 8x6 blocks.
  const int orig = blockIdx.x;
  const int xcd = orig & 7, sidx = orig >> 3;
  const int stl = sidx / 48, u = sidx % 48;
  const int stg = xcd + stl * 8;
  const int stx = stg % 6, sty = stg / 6;
  const int bx = stx * 8 + (u & 7);
  const int by = sty * 6 + (u >> 3);

  // staging lane geometry (BK=32 half: row=64B=4 chunks, chunk ^= row&3)
  const int rowL = w * 32 + (l >> 2);              // 0..255 (+p*16)
  const int chunkL = (l & 3) ^ ((l >> 2) & 3);
  const __bf16* gAb = at + (size_t)(bx * 256 + rowL) * 512 + chunkL * 8;
  const __bf16* gBb = bt + (size_t)(by * 256 + rowL) * 512 + chunkL * 8;

  f32x4 acc[8][4];
#pragma unroll
  for (int i = 0; i < 8; ++i)
#pragma unroll
    for (int j = 0; j < 4; ++j) acc[i][j] = (f32x4){0.f, 0.f, 0.f, 0.f};

  // stage part p (0/1) of half h into slot h&3
  auto STAGE = [&](int h, int p) {
    char* da = smem + (h & 3) * 32768 + w * 2048 + p * 1024;
    char* db = da + 16384;
    const int go = h * 32 + p * 16 * 512;
    async16(gAb + go, da);
    async16(gBb + go, db);
  };

  // prologue: halves 0,1,2
#pragma unroll
  for (int h = 0; h < 3; ++h) {
    STAGE(h, 0);
    STAGE(h, 1);
  }
  asm volatile("s_waitcnt vmcnt(8)" ::: "memory");
  __builtin_amdgcn_s_barrier();

  bf16x8 bfr[4];
#pragma unroll
  for (int h = 0; h < 16; ++h) {
    const char* A = smem + (h & 3) * 32768;
    const char* B = A + 16384;
#pragma unroll
    for (int ph = 0; ph < 2; ++ph) {
      // ds reads for this phase
      bf16x8 af[4];
      if (ph == 0) {
#pragma unroll
        for (int fj = 0; fj < 4; ++fj) {
          const int r = wc * 64 + fj * 16 + lr;
          bfr[fj] = *(const bf16x8*)(B + r * 64 + (lk ^ (lr & 3)) * 16);
        }
      }
#pragma unroll
      for (int i = 0; i < 4; ++i) {
        const int r = wr * 128 + (ph * 4 + i) * 16 + lr;
        af[i] = *(const bf16x8*)(A + r * 64 + (lk ^ (lr & 3)) * 16);
      }
      // stage-issue for half h+3
      if (h + 3 < 16) STAGE(h + 3, ph);
      // boundary vmcnt before final barrier of the half
      if (ph == 1) {
        if (h <= 12)      asm volatile("s_waitcnt vmcnt(8)" ::: "memory");
        else if (h == 13) asm volatile("s_waitcnt vmcnt(4)" ::: "memory");
        else if (h == 14) asm volatile("s_waitcnt vmcnt(0)" ::: "memory");
      }
      __builtin_amdgcn_s_barrier();
      asm volatile("s_waitcnt lgkmcnt(0)" ::: "memory");
      __builtin_amdgcn_s_setprio(1);
#pragma unroll
      for (int i = 0; i < 4; ++i)
#pragma unroll
        for (int fj = 0; fj < 4; ++fj)
          acc[ph * 4 + i][fj] =
              __builtin_amdgcn_mfma_f32_16x16x32_bf16(af[i], bfr[fj], acc[ph * 4 + i][fj], 0, 0, 0);
      __builtin_amdgcn_s_setprio(0);
      __builtin_amdgcn_s_barrier();
    }
  }

  // ---- op tile -> LDS bf16 as A2[pair][k'=e*32+d], chunk-XOR swizzled ----
#pragma unroll
  for (int fi = 0; fi < 8; ++fi) {
    const int i_l = wr * 4 + (fi >> 1);             // lane-uniform
#pragma unroll
    for (int fj = 0; fj < 4; ++fj) {
      const int col = wc * 64 + fj * 16 + lr;
      const int j_l = col >> 5, e = col & 31;
      const int pair = i_l * 8 + j_l;
      const int cw = e * 4 + (fi & 1) * 2 + (lk >> 1);
      const int phys = cw ^ (e & 7);
      bf16x4 pk;
      pk[0] = (__bf16)acc[fi][fj][0];
      pk[1] = (__bf16)acc[fi][fj][1];
      pk[2] = (__bf16)acc[fi][fj][2];
      pk[3] = (__bf16)acc[fi][fj][3];
      *(bf16x4*)(smem + pair * 2064 + phys * 16 + (lk & 1) * 8) = pk;
    }
  }
  asm volatile("s_waitcnt lgkmcnt(0)" ::: "memory");
  __builtin_amdgcn_s_barrier();

  // ---- GEMM2: C[64 pairs][128 p], K=1024; wave = 2 Mfrags x 2 Nfrags ----
  const int mg = w & 1, ng = w >> 1;
  f32x4 acc2[2][2];
#pragma unroll
  for (int a = 0; a < 2; ++a)
#pragma unroll
    for (int b = 0; b < 2; ++b) acc2[a][b] = (f32x4){0.f, 0.f, 0.f, 0.f};

#pragma unroll 2
  for (int kk = 0; kk < 32; ++kk) {
    const int phys = (kk * 4 + lk) ^ (kk & 7);
    bf16x8 a2[2], b2[2];
#pragma unroll
    for (int mf = 0; mf < 2; ++mf) {
      const int pair = mg * 32 + mf * 16 + lr;
      a2[mf] = *(const bf16x8*)(smem + pair * 2064 + phys * 16);
    }
    const int k = kk * 32 + lk * 8;
#pragma unroll
    for (int nf = 0; nf < 2; ++nf) {
      const int p = ng * 32 + nf * 16 + lr;
      b2[nf] = *(const bf16x8*)(wt + (size_t)p * 1024 + k);
    }
#pragma unroll
    for (int mf = 0; mf < 2; ++mf)
#pragma unroll
      for (int nf = 0; nf < 2; ++nf)
        acc2[mf][nf] = __builtin_amdgcn_mfma_f32_16x16x32_bf16(a2[mf], b2[nf], acc2[mf][nf], 0, 0, 0);
  }

#pragma unroll
  for (int mf = 0; mf < 2; ++mf)
#pragma unroll
    for (int r = 0; r < 4; ++r) {
      const int pair = mg * 32 + mf * 16 + lk * 4 + r;
      const int i = bx * 8 + (pair >> 3);
      const int j = by * 8 + (pair & 7);
      const float pm = mkf[i] * mkf[j];
#pragma unroll
      for (int nf = 0; nf < 2; ++nf) {
        const int p = ng * 32 + nf * 16 + lr;
        out[((size_t)i * DN + j) * DP + p] = acc2[mf][nf][r] * pm + b_out[p];
      }
    }
}

extern "C" void kernel_launch(void* const* d_in, const int* in_sizes, int n_in,
                              void* d_out, int out_size, void* d_ws, size_t ws_size,
                              hipStream_t stream) {
  const float* msa      = (const float*)d_in[0];
  const void*  mask     = d_in[1];
  const void*  msa_mask = d_in[2];
  const float* gamma    = (const float*)d_in[3];
  const float* beta     = (const float*)d_in[4];
  const float* w_hidden = (const float*)d_in[5];
  const float* w_out    = (const float*)d_in[6];
  const float* b_out    = (const float*)d_in[7];
  float* out = (float*)d_out;

  char* ws = (char*)d_ws;
  __bf16* at  = (__bf16*)ws;
  __bf16* bt  = (__bf16*)(ws + OFF_BT);
  __bf16* wt  = (__bf16*)(ws + OFF_WT);
  float*  inv = (float*)(ws + OFF_INV);
  float*  smf = (float*)(ws + OFF_SMF);
  float*  mkf = (float*)(ws + OFF_MKF);

  prep_kernel<<<1026, 128, 0, stream>>>(mask, msa_mask, w_out, wt, inv, smf, mkf);
  ln_proj_kernel<<<768, 256, 0, stream>>>(msa, gamma, beta, w_hidden, inv, smf, at, bt);
  fused_kernel<<<2304, 512, 0, stream>>>(at, bt, wt, mkf, b_out, out);
}

// Round 4
// 260.106 us; speedup vs baseline: 1.8551x; 1.2796x over previous
//
#include <hip/hip_runtime.h>

#define DN 384
#define DS 512
#define DMSA 64
#define DH 32
#define DP 128

typedef __bf16 bf16x8 __attribute__((ext_vector_type(8)));
typedef __bf16 bf16x4 __attribute__((ext_vector_type(4)));
typedef float f32x4 __attribute__((ext_vector_type(4)));

// ws layout (bytes)
#define OFF_BT  12582912u
#define OFF_WT  25165824u
#define OFF_INV 25427968u
#define OFF_SMF 25428224u
#define OFF_MKF 25430272u

__device__ __forceinline__ void async16(const void* g, void* l) {
  __builtin_amdgcn_global_load_lds((const __attribute__((address_space(1))) unsigned*)g,
                                   (__attribute__((address_space(3))) unsigned*)l, 16, 0, 0);
}

// ---------------------------------------------------------------------------
// prep: mask normalization, 1/num_msa, w_out -> wt2 bf16 [kk][p][32]
// (k = d*32+e reindexed to k' = e*32+d; kk = k'>>5, r = k'&31).
// ---------------------------------------------------------------------------
__global__ __launch_bounds__(128) void prep_kernel(const void* __restrict__ mask_raw,
                                                   const void* __restrict__ msa_mask_raw,
                                                   const float* __restrict__ w_out,
                                                   __bf16* __restrict__ wt,
                                                   float* __restrict__ invp,
                                                   float* __restrict__ smf,
                                                   float* __restrict__ mkf) {
  const int blk = blockIdx.x;
  const int tid = threadIdx.x;
  if (blk == 0) {
    __shared__ int sh[128];
    const unsigned int* u = (const unsigned int*)msa_mask_raw;
    int bad = (u[tid] > 1u) ? 1 : 0;
    sh[tid] = bad;
    __syncthreads();
    for (int off = 64; off > 0; off >>= 1) {
      if (tid < off) sh[tid] |= sh[tid + off];
      __syncthreads();
    }
    const int int_mode = (sh[0] == 0);
    __syncthreads();
    int cnt = 0;
    for (int q = tid; q < DS; q += 128) {
      float v;
      if (int_mode) v = (((const int*)msa_mask_raw)[q] != 0) ? 1.f : 0.f;
      else          v = (((const unsigned char*)msa_mask_raw)[q] != 0) ? 1.f : 0.f;
      smf[q] = v;
      cnt += (v != 0.f) ? 1 : 0;
    }
    sh[tid] = cnt;
    __syncthreads();
    for (int off = 64; off > 0; off >>= 1) {
      if (tid < off) sh[tid] += sh[tid + off];
      __syncthreads();
    }
    if (tid == 0) {
      float num = (float)sh[0];
      if (num < 1e-5f) num = 1e-5f;
      invp[0] = 1.0f / num;
    }
  } else if (blk == 1) {
    __shared__ int sh[128];
    const unsigned int* u = (const unsigned int*)mask_raw;
    int bad = 0;
    if (tid < 96) bad = (u[tid] > 1u) ? 1 : 0;
    sh[tid] = bad;
    __syncthreads();
    for (int off = 64; off > 0; off >>= 1) {
      if (tid < off) sh[tid] |= sh[tid + off];
      __syncthreads();
    }
    const int int_mode = (sh[0] == 0);
    __syncthreads();
    for (int q = tid; q < DN; q += 128) {
      float v;
      if (int_mode) v = (((const int*)mask_raw)[q] != 0) ? 1.f : 0.f;
      else          v = (((const unsigned char*)mask_raw)[q] != 0) ? 1.f : 0.f;
      mkf[q] = v;
    }
  } else {
    const int kw = blk - 2;          // k = d*32+e
    const int p = tid;               // 0..127
    const int kp = (kw & 31) * 32 + (kw >> 5);   // k' = e*32+d
    const int kk = kp >> 5, r = kp & 31;
    wt[((size_t)kk * 128 + p) * 32 + r] = (__bf16)w_out[(size_t)kw * DP + p];
  }
}

// ---------------------------------------------------------------------------
// ln_proj: LN(64) -> x@w_hidden -> mask/scale -> at/bt [n*32+c][s] bf16.
// ---------------------------------------------------------------------------
__global__ __launch_bounds__(256) void ln_proj_kernel(const float* __restrict__ msa,
                                                      const float* __restrict__ gamma,
                                                      const float* __restrict__ beta,
                                                      const float* __restrict__ w_hidden,
                                                      const float* __restrict__ invp,
                                                      const float* __restrict__ smf,
                                                      __bf16* __restrict__ at,
                                                      __bf16* __restrict__ bt) {
  __shared__ float wl[DMSA * 2 * DH];
  __shared__ float gl[DMSA], bl[DMSA];
  const int tid = threadIdx.x;
  for (int q = tid; q < DMSA * 2 * DH; q += 256) wl[q] = w_hidden[q];
  if (tid < DMSA) { gl[tid] = gamma[tid]; bl[tid] = beta[tid]; }
  __syncthreads();

  const int p = blockIdx.x * 256 + tid;
  const int n = p >> 9;
  const int s = p & 511;

  const float* mp = msa + ((size_t)s * DN + n) * DMSA;
  float x[64];
  float sum = 0.f, sq = 0.f;
#pragma unroll
  for (int q = 0; q < 16; ++q) {
    float4 v = ((const float4*)mp)[q];
    x[4 * q + 0] = v.x; x[4 * q + 1] = v.y; x[4 * q + 2] = v.z; x[4 * q + 3] = v.w;
    sum += v.x + v.y + v.z + v.w;
    sq  += v.x * v.x + v.y * v.y + v.z * v.z + v.w * v.w;
  }
  const float mu = sum * (1.f / 64.f);
  const float var = sq * (1.f / 64.f) - mu * mu;
  const float rstd = rsqrtf(var + 1e-5f);
#pragma unroll
  for (int d = 0; d < 64; ++d) x[d] = (x[d] - mu) * rstd * gl[d] + bl[d];

  const float sm = smf[s];
  const float sa = sm * invp[0];

  const size_t outbase = ((size_t)n * DH) * DS + s;
  for (int c = 0; c < DH; ++c) {
    float ha = 0.f, hb = 0.f;
#pragma unroll
    for (int d = 0; d < 64; ++d) {
      ha += x[d] * wl[d * 64 + c];
      hb += x[d] * wl[d * 64 + DH + c];
    }
    at[outbase + (size_t)c * DS] = (__bf16)(ha * sa);
    bt[outbase + (size_t)c * DS] = (__bf16)(hb * sm);
  }
}

// ---------------------------------------------------------------------------
// fused: GEMM1 256x256xK512, 16 halves (BK=32) on a 4-slot ring, ONE barrier
// + ONE counted vmcnt per half, 32 MFMA per segment. Then op->LDS ->
// GEMM2 64x128xK1024 (1 Nfrag x 4 Mfrags/wave, wt read once, prefetched).
// ---------------------------------------------------------------------------
__global__ __launch_bounds__(512, 2) void fused_kernel(const __bf16* __restrict__ at,
                                                       const __bf16* __restrict__ bt,
                                                       const __bf16* __restrict__ wt,
                                                       const float* __restrict__ mkf,
                                                       const float* __restrict__ b_out,
                                                       float* __restrict__ out) {
  // ring: 4 slots x (A 16KB + B 16KB) = 128KB; aliased: opl 64x2064B = 129KB
  __shared__ __align__(128) char smem[132096];

  const int tid = threadIdx.x;
  const int l = tid & 63, w = tid >> 6;
  const int lr = l & 15, lk = l >> 4;
  const int wr = w >> 2, wc = w & 3;

  // XCD-aware swizzle: 48 supertiles of 8x6 blocks.
  const int orig = blockIdx.x;
  const int xcd = orig & 7, sidx = orig >> 3;
  const int stl = sidx / 48, u = sidx % 48;
  const int stg = xcd + stl * 8;
  const int stx = stg % 6, sty = stg / 6;
  const int bx = stx * 8 + (u & 7);
  const int by = sty * 6 + (u >> 3);

  // staging lane geometry (BK=32 half: row=64B=4 chunks, chunk ^= row&3)
  const int rowL = w * 32 + (l >> 2);              // +p*16
  const int chunkL = (l & 3) ^ ((l >> 2) & 3);
  const __bf16* gAb = at + (size_t)(bx * 256 + rowL) * 512 + chunkL * 8;
  const __bf16* gBb = bt + (size_t)(by * 256 + rowL) * 512 + chunkL * 8;

  f32x4 acc[8][4];
#pragma unroll
  for (int i = 0; i < 8; ++i)
#pragma unroll
    for (int j = 0; j < 4; ++j) acc[i][j] = (f32x4){0.f, 0.f, 0.f, 0.f};

  // stage whole half h (4 asyncs) into slot h&3
  auto STAGE4 = [&](int h) {
    char* da = smem + (h & 3) * 32768 + w * 2048;
    char* db = da + 16384;
    const int go = h * 32;
    async16(gAb + go, da);
    async16(gAb + go + 16 * 512, da + 1024);
    async16(gBb + go, db);
    async16(gBb + go + 16 * 512, db + 1024);
  };

  STAGE4(0);
  STAGE4(1);
  STAGE4(2);

#pragma unroll
  for (int h = 0; h < 16; ++h) {
    if (h <= 13)      asm volatile("s_waitcnt vmcnt(8)" ::: "memory");
    else if (h == 14) asm volatile("s_waitcnt vmcnt(4)" ::: "memory");
    else              asm volatile("s_waitcnt vmcnt(0)" ::: "memory");
    __builtin_amdgcn_s_barrier();

    const char* A = smem + (h & 3) * 32768;
    const char* B = A + 16384;
    bf16x8 af[8], bfr[4];
#pragma unroll
    for (int fj = 0; fj < 4; ++fj) {
      const int r = wc * 64 + fj * 16 + lr;
      bfr[fj] = *(const bf16x8*)(B + r * 64 + (lk ^ (lr & 3)) * 16);
    }
#pragma unroll
    for (int fi = 0; fi < 8; ++fi) {
      const int r = wr * 128 + fi * 16 + lr;
      af[fi] = *(const bf16x8*)(A + r * 64 + (lk ^ (lr & 3)) * 16);
    }
    if (h < 13) STAGE4(h + 3);

    asm volatile("s_waitcnt lgkmcnt(0)" ::: "memory");
    __builtin_amdgcn_s_setprio(1);
#pragma unroll
    for (int fi = 0; fi < 8; ++fi)
#pragma unroll
      for (int fj = 0; fj < 4; ++fj)
        acc[fi][fj] = __builtin_amdgcn_mfma_f32_16x16x32_bf16(af[fi], bfr[fj], acc[fi][fj], 0, 0, 0);
    __builtin_amdgcn_s_setprio(0);
  }

  // barrier: all waves done reading the ring before op-writes clobber smem
  __builtin_amdgcn_s_barrier();

  // ---- op tile -> LDS bf16 as A2[pair][k'=e*32+d], chunk-XOR swizzled ----
#pragma unroll
  for (int fi = 0; fi < 8; ++fi) {
    const int i_l = wr * 4 + (fi >> 1);             // lane-uniform
#pragma unroll
    for (int fj = 0; fj < 4; ++fj) {
      const int col = wc * 64 + fj * 16 + lr;
      const int j_l = col >> 5, e = col & 31;
      const int pair = i_l * 8 + j_l;
      const int cw = e * 4 + (fi & 1) * 2 + (lk >> 1);
      const int phys = cw ^ (e & 7);
      bf16x4 pk;
      pk[0] = (__bf16)acc[fi][fj][0];
      pk[1] = (__bf16)acc[fi][fj][1];
      pk[2] = (__bf16)acc[fi][fj][2];
      pk[3] = (__bf16)acc[fi][fj][3];
      *(bf16x4*)(smem + pair * 2064 + phys * 16 + (lk & 1) * 8) = pk;
    }
  }

  // prefetch first wt fragment (hides L2 latency under the barrier)
  const __bf16* wp = wt + ((size_t)w * 16 + lr) * 32 + lk * 8;  // + kk*4096
  bf16x8 b2 = *(const bf16x8*)(wp);

  asm volatile("s_waitcnt lgkmcnt(0)" ::: "memory");
  __builtin_amdgcn_s_barrier();

  // ---- GEMM2: C[64 pairs][128 p], K=1024; wave w owns p-range w*16..+16 ----
  f32x4 acc2[4];
#pragma unroll
  for (int a = 0; a < 4; ++a) acc2[a] = (f32x4){0.f, 0.f, 0.f, 0.f};

#pragma unroll 4
  for (int kk = 0; kk < 32; ++kk) {
    bf16x8 b2n;
    if (kk < 31) b2n = *(const bf16x8*)(wp + (size_t)(kk + 1) * 4096);
    const int phys = (kk * 4 + lk) ^ (kk & 7);
    bf16x8 a2[4];
#pragma unroll
    for (int m2 = 0; m2 < 4; ++m2) {
      const int pair = m2 * 16 + lr;
      a2[m2] = *(const bf16x8*)(smem + pair * 2064 + phys * 16);
    }
#pragma unroll
    for (int m2 = 0; m2 < 4; ++m2)
      acc2[m2] = __builtin_amdgcn_mfma_f32_16x16x32_bf16(a2[m2], b2, acc2[m2], 0, 0, 0);
    b2 = b2n;
  }

  const int p = w * 16 + lr;
  const float bo = b_out[p];
#pragma unroll
  for (int m2 = 0; m2 < 4; ++m2)
#pragma unroll
    for (int r = 0; r < 4; ++r) {
      const int pair = m2 * 16 + lk * 4 + r;
      const int i = bx * 8 + (pair >> 3);
      const int j = by * 8 + (pair & 7);
      const float pm = mkf[i] * mkf[j];
      out[((size_t)i * DN + j) * DP + p] = acc2[m2][r] * pm + bo;
    }
}

extern "C" void kernel_launch(void* const* d_in, const int* in_sizes, int n_in,
                              void* d_out, int out_size, void* d_ws, size_t ws_size,
                              hipStream_t stream) {
  const float* msa      = (const float*)d_in[0];
  const void*  mask     = d_in[1];
  const void*  msa_mask = d_in[2];
  const float* gamma    = (const float*)d_in[3];
  const float* beta     = (const float*)d_in[4];
  const float* w_hidden = (const float*)d_in[5];
  const float* w_out    = (const float*)d_in[6];
  const float* b_out    = (const float*)d_in[7];
  float* out = (float*)d_out;

  char* ws = (char*)d_ws;
  __bf16* at  = (__bf16*)ws;
  __bf16* bt  = (__bf16*)(ws + OFF_BT);
  __bf16* wt  = (__bf16*)(ws + OFF_WT);
  float*  inv = (float*)(ws + OFF_INV);
  float*  smf = (float*)(ws + OFF_SMF);
  float*  mkf = (float*)(ws + OFF_MKF);

  prep_kernel<<<1026, 128, 0, stream>>>(mask, msa_mask, w_out, wt, inv, smf, mkf);
  ln_proj_kernel<<<768, 256, 0, stream>>>(msa, gamma, beta, w_hidden, inv, smf, at, bt);
  fused_kernel<<<2304, 512, 0, stream>>>(at, bt, wt, mkf, b_out, out);
}